// Round 9
// baseline (178.508 us; speedup 1.0000x reference)
//
#include <hip/hip_runtime.h>
#include <cstdint>

// CausalSelfAttention B=2 L=2048 D=1024 H=16 dh=64, fp32 in/out.
// R16: attn q-pair merge. R15 falsified the CU=bid%256 co-residency model
// (quadruple remap regressed 46.5->48.9). New model from counter arithmetic:
// attn is LDS-read-bound — all 4 waves read the identical Ks/Vs per tile
// (128KB/block-iter, 4x redundant) ~ 2000 cy/iter/CU = the observed 46us.
// Fix: q-tiles 2t and 2t+1 share the SAME key range (nk = t+1 both), so one
// block now processes both (128 q-rows): every kfrag/vf LDS read feeds two
// MFMAs -> LDS bytes per unit work halved, K/V staging halved. 512 blocks,
// monotone heavy-first. gemm_kqv/gemm_out/prep unchanged from R14.

#define LSEQ 2048
#define DM   1024
#define BL   4096   // B * LSEQ

using frag_ab = __attribute__((ext_vector_type(8))) short;     // 8 bf16
using half8   = __attribute__((ext_vector_type(8))) _Float16;  // 8 fp16
using half4   = __attribute__((ext_vector_type(4))) _Float16;
using half2_t = __attribute__((ext_vector_type(2))) _Float16;
using fp16x2  = __attribute__((ext_vector_type(2))) __fp16;
using f32x4   = __attribute__((ext_vector_type(4))) float;

__device__ __forceinline__ unsigned short f2bf(float f) {
  unsigned int u = __float_as_uint(f);
  u += 0x7fffu + ((u >> 16) & 1u);   // RNE (finite inputs only)
  return (unsigned short)(u >> 16);
}

__device__ __forceinline__ half2_t pkrtz(float a, float b) {
  const fp16x2 r = __builtin_amdgcn_cvt_pkrtz(a, b);
  return __builtin_bit_cast(half2_t, r);
}

__device__ __forceinline__ void load_lds16(const void* g, void* l) {
  __builtin_amdgcn_global_load_lds(
      (const __attribute__((address_space(1))) unsigned int*)g,
      (__attribute__((address_space(3))) unsigned int*)l, 16, 0, 0);
}

// ---------------- merged prep kernel ----------------
// bid <  4096          : cast x -> bf16 (1 float4 per thread)
// 4096 <= bid < 6144   : W_kq (1024x2048) -> wcat bf16 [2048x1024]
// 6144 <= bid < 7168   : W_v  (1024x1024) -> wcat+2M bf16
// 7168 <= bid < 8192   : W_o  (1024x1024) -> wot fp16

__global__ __launch_bounds__(256) void prep_kernel(
    const float* __restrict__ x, unsigned short* __restrict__ xb,
    const float* __restrict__ W_kq, const float* __restrict__ W_v,
    const float* __restrict__ W_o,
    unsigned short* __restrict__ wcat, _Float16* __restrict__ wot)
{
  const int bid = blockIdx.x;
  const int tid = threadIdx.x;

  if (bid < 4096) {
    const int i = bid * 256 + tid;
    const float4 v = *(const float4*)&x[(size_t)i * 4];
    ushort4 o;
    o.x = f2bf(v.x); o.y = f2bf(v.y); o.z = f2bf(v.z); o.w = f2bf(v.w);
    *(ushort4*)&xb[(size_t)i * 4] = o;
    return;
  }

  __shared__ float tile[32][33];
  const int r  = tid >> 3;
  const int c4 = (tid & 7) * 4;

  const float* W;
  int N, nb, kb, which;
  if (bid < 6144) {
    const int b2 = bid - 4096;
    W = W_kq; N = 2048; nb = (b2 & 63) * 32; kb = (b2 >> 6) * 32; which = 0;
  } else if (bid < 7168) {
    const int b2 = bid - 6144;
    W = W_v;  N = 1024; nb = (b2 & 31) * 32; kb = (b2 >> 5) * 32; which = 1;
  } else {
    const int b2 = bid - 7168;
    W = W_o;  N = 1024; nb = (b2 & 31) * 32; kb = (b2 >> 5) * 32; which = 2;
  }

  const float4 v = *(const float4*)&W[(size_t)(kb + r) * N + nb + c4];
  tile[r][c4 + 0] = v.x; tile[r][c4 + 1] = v.y;
  tile[r][c4 + 2] = v.z; tile[r][c4 + 3] = v.w;
  __syncthreads();

  if (which == 2) {
    half4 o;
    o[0] = (_Float16)tile[c4 + 0][r];
    o[1] = (_Float16)tile[c4 + 1][r];
    o[2] = (_Float16)tile[c4 + 2][r];
    o[3] = (_Float16)tile[c4 + 3][r];
    *(half4*)&wot[(size_t)(nb + r) * 1024 + kb + c4] = o;
  } else {
    ushort4 o;
    o.x = f2bf(tile[c4 + 0][r]);
    o.y = f2bf(tile[c4 + 1][r]);
    o.z = f2bf(tile[c4 + 2][r]);
    o.w = f2bf(tile[c4 + 3][r]);
    unsigned short* dst = (which == 0) ? wcat : wcat + 2097152;
    *(ushort4*)&dst[(size_t)(nb + r) * 1024 + kb + c4] = o;
  }
}

// ---------------- fused kqv GEMM (frag-preload pipeline) ----------------
// A = xb [4096x1024] bf16, Bt = wcat [3072x1024] bf16
// cols <  2048 : kqb[row][col] = bf16((acc+b_kq[col]) * (col>=1024 ? s : 1))
//                s = 0.125 * log2(e)  (softmax runs in base-2)
// cols >= 2048 : vtb[col-2048][row] = fp16(acc + b_v[col-2048])   (V^T)

__global__ __launch_bounds__(256, 3) void gemm_kqv(
    const unsigned short* __restrict__ A, const unsigned short* __restrict__ Bt,
    const float* __restrict__ b_kq, const float* __restrict__ b_v,
    unsigned short* __restrict__ kqb, _Float16* __restrict__ vtb)
{
  const int tid  = threadIdx.x;
  const int lane = tid & 63;
  const int w    = tid >> 6;
  const int wm   = (w >> 1) * 64;
  const int wn   = (w & 1) * 64;
  const int n0   = blockIdx.x * 128;
  const int m0   = blockIdx.y * 128;
  const int quad = lane >> 4;
  const int l15  = lane & 15;
  const int K    = 1024;

  __shared__ __align__(16) unsigned short As[128 * 64];
  __shared__ __align__(16) unsigned short Bs[128 * 64];

  const int srow = lane >> 3;
  const int sc   = (lane & 7) ^ srow;

  const unsigned short* gA = A  + (size_t)(m0 + w * 32 + srow) * K + sc * 8;
  const unsigned short* gB = Bt + (size_t)(n0 + w * 32 + srow) * K + sc * 8;

#define STAGE_AB(K0)                                                           \
  {                                                                            \
    _Pragma("unroll")                                                          \
    for (int i = 0; i < 4; ++i) {                                              \
      load_lds16(gA + (size_t)i * 8 * K + (K0),                                \
                 &As[(w * 32 + i * 8) * 64 + lane * 8]);                       \
      load_lds16(gB + (size_t)i * 8 * K + (K0),                                \
                 &Bs[(w * 32 + i * 8) * 64 + lane * 8]);                       \
    }                                                                          \
  }

  f32x4 acc[4][4] = {};

  STAGE_AB(0);
  asm volatile("s_waitcnt vmcnt(0)\n\ts_barrier" ::: "memory");

  for (int k0 = 0; k0 < K; k0 += 64) {
    // LDS -> registers: all fragments of this K-tile
    frag_ab af[2][4], bf[2][4];
#pragma unroll
    for (int kf = 0; kf < 2; ++kf)
#pragma unroll
      for (int t = 0; t < 4; ++t) {
        const int ra = wm + t * 16 + l15;
        const int pa = (kf * 4 + quad) ^ (ra & 7);
        af[kf][t] = *(const frag_ab*)&As[ra * 64 + pa * 8];
        const int rb = wn + t * 16 + l15;
        const int pb = (kf * 4 + quad) ^ (rb & 7);
        bf[kf][t] = *(const frag_ab*)&Bs[rb * 64 + pb * 8];
      }
    // all ds_reads done -> LDS free for next stage
    asm volatile("s_waitcnt lgkmcnt(0)\n\ts_barrier" ::: "memory");
    if (k0 + 64 < K) STAGE_AB(k0 + 64);   // flies under the MFMAs below

    __builtin_amdgcn_s_setprio(1);
#pragma unroll
    for (int kf = 0; kf < 2; ++kf)
#pragma unroll
      for (int i = 0; i < 4; ++i)
#pragma unroll
        for (int j = 0; j < 4; ++j)
          acc[i][j] = __builtin_amdgcn_mfma_f32_16x16x32_bf16(
              af[kf][i], bf[kf][j], acc[i][j], 0, 0, 0);
    __builtin_amdgcn_s_setprio(0);

    asm volatile("s_waitcnt vmcnt(0)\n\ts_barrier" ::: "memory");
  }
#undef STAGE_AB

  if (n0 >= 2048) {
#pragma unroll
    for (int i = 0; i < 4; ++i)
#pragma unroll
      for (int j = 0; j < 4; ++j) {
        const int row0 = m0 + wm + i * 16 + quad * 4;
        const int col  = n0 - 2048 + wn + j * 16 + l15;
        const float bv = b_v[col];
        half4 pk;
        pk[0] = (_Float16)(acc[i][j][0] + bv);
        pk[1] = (_Float16)(acc[i][j][1] + bv);
        pk[2] = (_Float16)(acc[i][j][2] + bv);
        pk[3] = (_Float16)(acc[i][j][3] + bv);
        *(half4*)&vtb[(size_t)col * BL + row0] = pk;
      }
  } else {
    // 0.125 * log2(e): softmax computed as exp2 of these logits
    const float sc2 = (n0 + wn >= 1024) ? 0.18033688011112042f : 1.0f;
#pragma unroll
    for (int i = 0; i < 4; ++i)
#pragma unroll
      for (int j = 0; j < 4; ++j) {
        const int row0 = m0 + wm + i * 16 + quad * 4;
        const int col  = n0 + wn + j * 16 + l15;
        const float bv = b_kq[col];
#pragma unroll
        for (int r = 0; r < 4; ++r)
          kqb[(size_t)(row0 + r) * 2048 + col] = f2bf((acc[i][j][r] + bv) * sc2);
      }
  }
}

// ---------------- output GEMM (fp16, frag-preload pipeline) ----------------

__global__ __launch_bounds__(256, 2) void gemm_out(
    const _Float16* __restrict__ A, const _Float16* __restrict__ Bt,
    const float* __restrict__ bias, float* __restrict__ C)
{
  const int tid  = threadIdx.x;
  const int lane = tid & 63;
  const int w    = tid >> 6;
  const int wm   = (w >> 1) * 64;   // 0 / 64
  const int wn   = (w & 1) * 32;    // 0 / 32
  const int n0   = blockIdx.x * 64;
  const int m0   = blockIdx.y * 128;
  const int quad = lane >> 4;
  const int l15  = lane & 15;
  const int K    = 1024;

  __shared__ __align__(16) _Float16 As[128 * 64];
  __shared__ __align__(16) _Float16 Bs[64 * 64];

  const int srow = lane >> 3;
  const int sc   = (lane & 7) ^ srow;

  const _Float16* gA = A  + (size_t)(m0 + w * 32 + srow) * K + sc * 8;
  const _Float16* gB = Bt + (size_t)(n0 + w * 16 + srow) * K + sc * 8;

#define STAGE_AB(K0)                                                           \
  {                                                                            \
    _Pragma("unroll")                                                          \
    for (int i = 0; i < 4; ++i)                                                \
      load_lds16(gA + (size_t)i * 8 * K + (K0),                                \
                 &As[(w * 32 + i * 8) * 64 + lane * 8]);                       \
    _Pragma("unroll")                                                          \
    for (int i = 0; i < 2; ++i)                                                \
      load_lds16(gB + (size_t)i * 8 * K + (K0),                                \
                 &Bs[(w * 16 + i * 8) * 64 + lane * 8]);                       \
  }

  f32x4 acc[4][2] = {};

  STAGE_AB(0);
  asm volatile("s_waitcnt vmcnt(0)\n\ts_barrier" ::: "memory");

  for (int k0 = 0; k0 < K; k0 += 64) {
    half8 af[2][4], bf[2][2];
#pragma unroll
    for (int kf = 0; kf < 2; ++kf) {
#pragma unroll
      for (int t = 0; t < 4; ++t) {
        const int ra = wm + t * 16 + l15;
        const int pa = (kf * 4 + quad) ^ (ra & 7);
        af[kf][t] = *(const half8*)&As[ra * 64 + pa * 8];
      }
#pragma unroll
      for (int t = 0; t < 2; ++t) {
        const int rb = wn + t * 16 + l15;
        const int pb = (kf * 4 + quad) ^ (rb & 7);
        bf[kf][t] = *(const half8*)&Bs[rb * 64 + pb * 8];
      }
    }
    asm volatile("s_waitcnt lgkmcnt(0)\n\ts_barrier" ::: "memory");
    if (k0 + 64 < K) STAGE_AB(k0 + 64);

    __builtin_amdgcn_s_setprio(1);
#pragma unroll
    for (int kf = 0; kf < 2; ++kf)
#pragma unroll
      for (int i = 0; i < 4; ++i)
#pragma unroll
        for (int j = 0; j < 2; ++j)
          acc[i][j] = __builtin_amdgcn_mfma_f32_16x16x32_f16(
              af[kf][i], bf[kf][j], acc[i][j], 0, 0, 0);
    __builtin_amdgcn_s_setprio(0);

    asm volatile("s_waitcnt vmcnt(0)\n\ts_barrier" ::: "memory");
  }
#undef STAGE_AB

#pragma unroll
  for (int i = 0; i < 4; ++i)
#pragma unroll
    for (int j = 0; j < 2; ++j) {
      const int row0 = m0 + wm + i * 16 + quad * 4;
      const int col  = n0 + wn + j * 16 + l15;
      const float bv = bias[col];
#pragma unroll
      for (int r = 0; r < 4; ++r)
        C[(size_t)(row0 + r) * DM + col] = acc[i][j][r] + bv;
    }
}

// ---------------- flash attention (q-pair blocks, pipelined) ----------------
// kq: bf16 [BL][2048] (k cols 0..1023, q cols 1024..2047 pre-scaled 0.125*log2e)
// vt: fp16 [1024][BL] (V^T); att: fp16 [BL][1024]
// 512 blocks: t = 15-(bx>>5) (heavy first), bh = bx&31. Block processes
// q-rows t*128..t*128+127 as TWO 64-row tiles (A: +0..63, B: +64..127) with
// IDENTICAL key range nk = t+1 -> every Ks/Vs LDS read feeds 2 MFMAs.
// Per tile: counted-vmcnt K/V pipeline, base-2 softmax, defer-max THR=8.

__global__ __launch_bounds__(256) void attn_mfma(
    const unsigned short* __restrict__ kq, const _Float16* __restrict__ vt,
    _Float16* __restrict__ att)
{
  const int tid  = threadIdx.x;
  const int lane = tid & 63;
  const int w    = tid >> 6;
  const int bx   = blockIdx.x;
  const int t    = 15 - (bx >> 5);   // heavy pairs first
  const int bh   = bx & 31;
  const int b    = bh >> 4;
  const int h    = bh & 15;
  const int q0   = t * 128;
  const int nk   = t + 1;
  const int quad = lane >> 4;
  const int l15  = lane & 15;

  __shared__ __align__(16) unsigned short Ks[128 * 64];  // keys x d, bf16 (16KB)
  __shared__ __align__(16) _Float16      Vs[64 * 128];   // d x keys, fp16 (16KB)

  // ---- stage Q (128x64) into Ks region, read frags, then reuse Ks for K ----
#pragma unroll
  for (int i = 0; i < 4; ++i) {
    const int L = i * 256 + tid;        // 0..1023
    const int row = L >> 3, c = L & 7;
    const unsigned short* g = kq + (size_t)(b * LSEQ + q0 + row) * 2048
                                 + DM + h * 64 + ((c ^ (row & 7)) * 8);
    load_lds16(g, &Ks[(size_t)L * 8]);
  }
  asm volatile("s_waitcnt vmcnt(0)\n\ts_barrier" ::: "memory");
  frag_ab qaA[2], qaB[2];
#pragma unroll
  for (int kf = 0; kf < 2; ++kf) {
    const int rowA = w * 16 + l15;
    const int cA = (kf * 4 + quad) ^ (rowA & 7);
    qaA[kf] = *(const frag_ab*)&Ks[rowA * 64 + cA * 8];
    const int rowB = 64 + w * 16 + l15;
    const int cB = (kf * 4 + quad) ^ (rowB & 7);
    qaB[kf] = *(const frag_ab*)&Ks[rowB * 64 + cB * 8];
  }
  asm volatile("s_waitcnt lgkmcnt(0)\n\ts_barrier" ::: "memory");  // Ks free

  // staging helpers: 4 DMA loads per thread each
#define STAGE_K(K0)                                                            \
  {                                                                            \
    _Pragma("unroll")                                                          \
    for (int i = 0; i < 4; ++i) {                                              \
      const int L = i * 256 + tid;                                             \
      const int row = L >> 3, c = L & 7;                                       \
      const unsigned short* g = kq + (size_t)(b * LSEQ + (K0) + row) * 2048    \
                                   + h * 64 + ((c ^ (row & 7)) * 8);           \
      load_lds16(g, &Ks[(size_t)L * 8]);                                       \
    }                                                                          \
  }
#define STAGE_V(K0)                                                            \
  {                                                                            \
    _Pragma("unroll")                                                          \
    for (int i = 0; i < 4; ++i) {                                              \
      const int L = i * 256 + tid;                                             \
      const int row = L >> 4, c16 = L & 15;                                    \
      const _Float16* g = vt + (size_t)(h * 64 + row) * BL                     \
                             + b * LSEQ + (K0) + ((c16 ^ (row & 15)) * 8);     \
      load_lds16(g, &Vs[(size_t)L * 8]);                                       \
    }                                                                          \
  }

  STAGE_K(0);
  STAGE_V(0);

  f32x4 oaccA[4] = {}, oaccB[4] = {};
  float mrowA = -3e38f, lrowA = 0.f, mrowB = -3e38f, lrowB = 0.f;

  for (int kt = 0; kt < nk; ++kt) {
    const int k0 = kt * 128;
    const bool more = (kt + 1 < nk);

    // K(kt) landed (own 4 oldest); V(kt) may still be in flight
    asm volatile("s_waitcnt vmcnt(4)\n\ts_barrier" ::: "memory");

    // S^T = K @ Q^T for both q-tiles; each kfrag read feeds 2 MFMAs
    f32x4 stA[8], stB[8];
    __builtin_amdgcn_s_setprio(1);
#pragma unroll
    for (int mt = 0; mt < 8; ++mt) {
      f32x4 sA = {}, sB = {};
#pragma unroll
      for (int kf = 0; kf < 2; ++kf) {
        const int row = mt * 16 + l15;
        const int c = (kf * 4 + quad) ^ (row & 7);
        const frag_ab kfrag = *(const frag_ab*)&Ks[row * 64 + c * 8];
        sA = __builtin_amdgcn_mfma_f32_16x16x32_bf16(kfrag, qaA[kf], sA, 0, 0, 0);
        sB = __builtin_amdgcn_mfma_f32_16x16x32_bf16(kfrag, qaB[kf], sB, 0, 0, 0);
      }
      stA[mt] = sA; stB[mt] = sB;
    }
    __builtin_amdgcn_s_setprio(0);

    // all waves done reading Ks -> safe to overwrite with K(kt+1)
    asm volatile("s_waitcnt lgkmcnt(0)\n\ts_barrier" ::: "memory");
    if (more) STAGE_K(k0 + 128);   // hides under softmax + PV

    if (kt == nk - 1) {   // causal mask (last tile only)
      const int qgA = q0 + w * 16 + l15;
      const int qgB = qgA + 64;
#pragma unroll
      for (int mt = 0; mt < 8; ++mt)
#pragma unroll
        for (int r = 0; r < 4; ++r) {
          const int key = k0 + mt * 16 + quad * 4 + r;
          if (key > qgA) stA[mt][r] = -3e38f;
          if (key > qgB) stB[mt][r] = -3e38f;
        }
    }

    // ---- online softmax (base-2), defer-max THR=8, both tiles ----
#define SOFTMAX(ST, MROW, LROW, PF, OACC)                                      \
    {                                                                          \
      float mx = fmaxf(ST[0][0], ST[0][1]);                                    \
      mx = fmaxf(fmaxf(mx, ST[0][2]), ST[0][3]);                               \
      _Pragma("unroll")                                                        \
      for (int mt = 1; mt < 8; ++mt) {                                         \
        mx = fmaxf(fmaxf(mx, ST[mt][0]), ST[mt][1]);                           \
        mx = fmaxf(fmaxf(mx, ST[mt][2]), ST[mt][3]);                           \
      }                                                                        \
      mx = fmaxf(mx, __shfl_xor(mx, 16));                                      \
      mx = fmaxf(mx, __shfl_xor(mx, 32));                                      \
      if (!__all(mx - MROW <= 8.0f)) {                                         \
        const float mnew  = fmaxf(MROW, mx);                                   \
        const float alpha = __builtin_amdgcn_exp2f(MROW - mnew);               \
        float aq[4];                                                           \
        _Pragma("unroll")                                                      \
        for (int r = 0; r < 4; ++r) aq[r] = __shfl(alpha, quad * 4 + r);       \
        _Pragma("unroll")                                                      \
        for (int dt = 0; dt < 4; ++dt)                                         \
          _Pragma("unroll")                                                    \
          for (int r = 0; r < 4; ++r) OACC[dt][r] *= aq[r];                    \
        LROW *= alpha;                                                         \
        MROW = mnew;                                                           \
      }                                                                        \
      float rs0 = 0.f, rs1 = 0.f, rs2 = 0.f, rs3 = 0.f;                        \
      _Pragma("unroll")                                                        \
      for (int mt = 0; mt < 8; ++mt) {                                         \
        const float e0 = __builtin_amdgcn_exp2f(ST[mt][0] - MROW);             \
        const float e1 = __builtin_amdgcn_exp2f(ST[mt][1] - MROW);             \
        const float e2 = __builtin_amdgcn_exp2f(ST[mt][2] - MROW);             \
        const float e3 = __builtin_amdgcn_exp2f(ST[mt][3] - MROW);             \
        rs0 += e0; rs1 += e1; rs2 += e2; rs3 += e3;                            \
        const half2_t p01 = pkrtz(e0, e1);                                     \
        const half2_t p23 = pkrtz(e2, e3);                                     \
        half4 p;                                                               \
        p[0] = p01[0]; p[1] = p01[1]; p[2] = p23[0]; p[3] = p23[1];            \
        PF[mt] = p;                                                            \
      }                                                                        \
      float rsum = (rs0 + rs1) + (rs2 + rs3);                                  \
      rsum += __shfl_xor(rsum, 16);                                            \
      rsum += __shfl_xor(rsum, 32);                                            \
      LROW += rsum;                                                            \
    }

    half4 pfA[8], pfB[8];
    SOFTMAX(stA, mrowA, lrowA, pfA, oaccA)
    SOFTMAX(stB, mrowB, lrowB, pfB, oaccB)
#undef SOFTMAX

    // V(kt) landed (own 4 oldest remaining); K(kt+1) may still be in flight
    if (more) {
      asm volatile("s_waitcnt vmcnt(4)\n\ts_barrier" ::: "memory");
    } else {
      asm volatile("s_waitcnt vmcnt(0)\n\ts_barrier" ::: "memory");
    }

    // O += P @ V, both tiles; each vf read feeds 2 MFMAs
    __builtin_amdgcn_s_setprio(1);
#pragma unroll
    for (int c8 = 0; c8 < 8; ++c8) {
#pragma unroll
      for (int dt = 0; dt < 4; ++dt) {
        const int g16 = 2 * c8 + (quad >> 1);
        const half4 vf = *(const half4*)&Vs[(dt * 16 + l15) * 128
                                            + ((g16 ^ l15) << 3) + ((quad & 1) << 2)];
        oaccA[dt] = __builtin_amdgcn_mfma_f32_16x16x16f16(pfA[c8], vf, oaccA[dt], 0, 0, 0);
        oaccB[dt] = __builtin_amdgcn_mfma_f32_16x16x16f16(pfB[c8], vf, oaccB[dt], 0, 0, 0);
      }
    }
    __builtin_amdgcn_s_setprio(0);

    if (more) {
      // all waves done reading Vs -> safe to overwrite with V(kt+1)
      asm volatile("s_waitcnt lgkmcnt(0)\n\ts_barrier" ::: "memory");
      STAGE_V(k0 + 128);   // hides under next S^T
    }
  }

  // epilogue: divide by l, store fp16 (both tiles)
  float lqA[4], lqB[4];
#pragma unroll
  for (int r = 0; r < 4; ++r) {
    lqA[r] = 1.0f / __shfl(lrowA, quad * 4 + r);
    lqB[r] = 1.0f / __shfl(lrowB, quad * 4 + r);
  }
#pragma unroll
  for (int dt = 0; dt < 4; ++dt)
#pragma unroll
    for (int r = 0; r < 4; ++r) {
      const int rowA = b * LSEQ + q0 + w * 16 + quad * 4 + r;
      const int col  = h * 64 + dt * 16 + l15;
      att[(size_t)rowA * DM + col] = (_Float16)(oaccA[dt][r] * lqA[r]);
      att[(size_t)(rowA + 64) * DM + col] = (_Float16)(oaccB[dt][r] * lqB[r]);
    }
#undef STAGE_K
#undef STAGE_V
}

// ---------------- launcher ----------------

extern "C" void kernel_launch(void* const* d_in, const int* in_sizes, int n_in,
                              void* d_out, int out_size, void* d_ws, size_t ws_size,
                              hipStream_t stream)
{
  const float* x    = (const float*)d_in[0];
  const float* W_kq = (const float*)d_in[1];
  const float* b_kq = (const float*)d_in[2];
  const float* W_v  = (const float*)d_in[3];
  const float* b_v  = (const float*)d_in[4];
  const float* W_o  = (const float*)d_in[5];
  const float* b_o  = (const float*)d_in[6];

  unsigned short* ws   = (unsigned short*)d_ws;
  unsigned short* xb   = ws;                    // 4096*1024 bf16
  unsigned short* wcat = xb   + 4194304;        // 3072*1024 bf16
  _Float16*       wot  = (_Float16*)(wcat + 3145728);      // 1024*1024 fp16
  unsigned short* kqb  = (unsigned short*)(wot + 1048576); // 4096*2048 bf16
  _Float16*       vtb  = (_Float16*)(kqb + 8388608);       // 1024*4096 fp16
  _Float16*       attb = vtb + 4194304;         // 4096*1024 fp16

  // merged prep (cast + 3 transposes)
  prep_kernel<<<8192, 256, 0, stream>>>(x, xb, W_kq, W_v, W_o, wcat, wot);
  // fused kq + v GEMM (24 x 32 = 768 blocks)
  gemm_kqv<<<dim3(24, 32), 256, 0, stream>>>(xb, wcat, b_kq, b_v, kqb, vtb);
  // attention (16 q-pairs x 32 bh = 512 blocks, heavy-first)
  attn_mfma<<<512, 256, 0, stream>>>(kqb, vtb, attb);
  // out = att @ Wo^T + b_o (16 x 32 = 512 blocks, 128x64 tiles)
  gemm_out<<<dim3(16, 32), 256, 0, stream>>>(attb, wot, b_o, (float*)d_out);
}

// Round 10
// 175.484 us; speedup vs baseline: 1.0172x; 1.0172x over previous
//
#include <hip/hip_runtime.h>
#include <cstdint>

// CausalSelfAttention B=2 L=2048 D=1024 H=16 dh=64, fp32 in/out.
// R17: (a) attn/gemm_kqv/prep restored to R14-exact (best measured total
// 169.4us; R15 quadruple remap and R16 q-pair merge both regressed — attn's
// 46us state depends on 4 resident blocks/CU for TLP; R16 also proved bank
// conflicts are NOT the attn limiter: halving them cost time via occupancy).
// (b) NEW: gemm_out LDS double-buffer (48KB, free — grid binds occupancy at
// 2/CU): per half-K-step [vmcnt0+bar][STAGE next->alt][frag-read cur][MFMA].
// Loads wait a full phase (~450cy) instead of ~250cy, barriers 2->1 per
// K-step. gemm_kqv keeps single buffer (dbuf would cut 3->2 blocks/CU).

#define LSEQ 2048
#define DM   1024
#define BL   4096   // B * LSEQ

using frag_ab = __attribute__((ext_vector_type(8))) short;     // 8 bf16
using half8   = __attribute__((ext_vector_type(8))) _Float16;  // 8 fp16
using half4   = __attribute__((ext_vector_type(4))) _Float16;
using half2_t = __attribute__((ext_vector_type(2))) _Float16;
using fp16x2  = __attribute__((ext_vector_type(2))) __fp16;
using f32x4   = __attribute__((ext_vector_type(4))) float;

__device__ __forceinline__ unsigned short f2bf(float f) {
  unsigned int u = __float_as_uint(f);
  u += 0x7fffu + ((u >> 16) & 1u);   // RNE (finite inputs only)
  return (unsigned short)(u >> 16);
}

__device__ __forceinline__ half2_t pkrtz(float a, float b) {
  const fp16x2 r = __builtin_amdgcn_cvt_pkrtz(a, b);
  return __builtin_bit_cast(half2_t, r);
}

__device__ __forceinline__ void load_lds16(const void* g, void* l) {
  __builtin_amdgcn_global_load_lds(
      (const __attribute__((address_space(1))) unsigned int*)g,
      (__attribute__((address_space(3))) unsigned int*)l, 16, 0, 0);
}

// ---------------- merged prep kernel ----------------
// bid <  4096          : cast x -> bf16 (1 float4 per thread)
// 4096 <= bid < 6144   : W_kq (1024x2048) -> wcat bf16 [2048x1024]
// 6144 <= bid < 7168   : W_v  (1024x1024) -> wcat+2M bf16
// 7168 <= bid < 8192   : W_o  (1024x1024) -> wot fp16

__global__ __launch_bounds__(256) void prep_kernel(
    const float* __restrict__ x, unsigned short* __restrict__ xb,
    const float* __restrict__ W_kq, const float* __restrict__ W_v,
    const float* __restrict__ W_o,
    unsigned short* __restrict__ wcat, _Float16* __restrict__ wot)
{
  const int bid = blockIdx.x;
  const int tid = threadIdx.x;

  if (bid < 4096) {
    const int i = bid * 256 + tid;
    const float4 v = *(const float4*)&x[(size_t)i * 4];
    ushort4 o;
    o.x = f2bf(v.x); o.y = f2bf(v.y); o.z = f2bf(v.z); o.w = f2bf(v.w);
    *(ushort4*)&xb[(size_t)i * 4] = o;
    return;
  }

  __shared__ float tile[32][33];
  const int r  = tid >> 3;
  const int c4 = (tid & 7) * 4;

  const float* W;
  int N, nb, kb, which;
  if (bid < 6144) {
    const int b2 = bid - 4096;
    W = W_kq; N = 2048; nb = (b2 & 63) * 32; kb = (b2 >> 6) * 32; which = 0;
  } else if (bid < 7168) {
    const int b2 = bid - 6144;
    W = W_v;  N = 1024; nb = (b2 & 31) * 32; kb = (b2 >> 5) * 32; which = 1;
  } else {
    const int b2 = bid - 7168;
    W = W_o;  N = 1024; nb = (b2 & 31) * 32; kb = (b2 >> 5) * 32; which = 2;
  }

  const float4 v = *(const float4*)&W[(size_t)(kb + r) * N + nb + c4];
  tile[r][c4 + 0] = v.x; tile[r][c4 + 1] = v.y;
  tile[r][c4 + 2] = v.z; tile[r][c4 + 3] = v.w;
  __syncthreads();

  if (which == 2) {
    half4 o;
    o[0] = (_Float16)tile[c4 + 0][r];
    o[1] = (_Float16)tile[c4 + 1][r];
    o[2] = (_Float16)tile[c4 + 2][r];
    o[3] = (_Float16)tile[c4 + 3][r];
    *(half4*)&wot[(size_t)(nb + r) * 1024 + kb + c4] = o;
  } else {
    ushort4 o;
    o.x = f2bf(tile[c4 + 0][r]);
    o.y = f2bf(tile[c4 + 1][r]);
    o.z = f2bf(tile[c4 + 2][r]);
    o.w = f2bf(tile[c4 + 3][r]);
    unsigned short* dst = (which == 0) ? wcat : wcat + 2097152;
    *(ushort4*)&dst[(size_t)(nb + r) * 1024 + kb + c4] = o;
  }
}

// ---------------- fused kqv GEMM (frag-preload pipeline, R14) ----------------
// A = xb [4096x1024] bf16, Bt = wcat [3072x1024] bf16
// cols <  2048 : kqb[row][col] = bf16((acc+b_kq[col]) * (col>=1024 ? s : 1))
//                s = 0.125 * log2(e)  (softmax runs in base-2)
// cols >= 2048 : vtb[col-2048][row] = fp16(acc + b_v[col-2048])   (V^T)

__global__ __launch_bounds__(256, 3) void gemm_kqv(
    const unsigned short* __restrict__ A, const unsigned short* __restrict__ Bt,
    const float* __restrict__ b_kq, const float* __restrict__ b_v,
    unsigned short* __restrict__ kqb, _Float16* __restrict__ vtb)
{
  const int tid  = threadIdx.x;
  const int lane = tid & 63;
  const int w    = tid >> 6;
  const int wm   = (w >> 1) * 64;
  const int wn   = (w & 1) * 64;
  const int n0   = blockIdx.x * 128;
  const int m0   = blockIdx.y * 128;
  const int quad = lane >> 4;
  const int l15  = lane & 15;
  const int K    = 1024;

  __shared__ __align__(16) unsigned short As[128 * 64];
  __shared__ __align__(16) unsigned short Bs[128 * 64];

  const int srow = lane >> 3;
  const int sc   = (lane & 7) ^ srow;

  const unsigned short* gA = A  + (size_t)(m0 + w * 32 + srow) * K + sc * 8;
  const unsigned short* gB = Bt + (size_t)(n0 + w * 32 + srow) * K + sc * 8;

#define STAGE_AB(K0)                                                           \
  {                                                                            \
    _Pragma("unroll")                                                          \
    for (int i = 0; i < 4; ++i) {                                              \
      load_lds16(gA + (size_t)i * 8 * K + (K0),                                \
                 &As[(w * 32 + i * 8) * 64 + lane * 8]);                       \
      load_lds16(gB + (size_t)i * 8 * K + (K0),                                \
                 &Bs[(w * 32 + i * 8) * 64 + lane * 8]);                       \
    }                                                                          \
  }

  f32x4 acc[4][4] = {};

  STAGE_AB(0);
  asm volatile("s_waitcnt vmcnt(0)\n\ts_barrier" ::: "memory");

  for (int k0 = 0; k0 < K; k0 += 64) {
    // LDS -> registers: all fragments of this K-tile
    frag_ab af[2][4], bf[2][4];
#pragma unroll
    for (int kf = 0; kf < 2; ++kf)
#pragma unroll
      for (int t = 0; t < 4; ++t) {
        const int ra = wm + t * 16 + l15;
        const int pa = (kf * 4 + quad) ^ (ra & 7);
        af[kf][t] = *(const frag_ab*)&As[ra * 64 + pa * 8];
        const int rb = wn + t * 16 + l15;
        const int pb = (kf * 4 + quad) ^ (rb & 7);
        bf[kf][t] = *(const frag_ab*)&Bs[rb * 64 + pb * 8];
      }
    // all ds_reads done -> LDS free for next stage
    asm volatile("s_waitcnt lgkmcnt(0)\n\ts_barrier" ::: "memory");
    if (k0 + 64 < K) STAGE_AB(k0 + 64);   // flies under the MFMAs below

    __builtin_amdgcn_s_setprio(1);
#pragma unroll
    for (int kf = 0; kf < 2; ++kf)
#pragma unroll
      for (int i = 0; i < 4; ++i)
#pragma unroll
        for (int j = 0; j < 4; ++j)
          acc[i][j] = __builtin_amdgcn_mfma_f32_16x16x32_bf16(
              af[kf][i], bf[kf][j], acc[i][j], 0, 0, 0);
    __builtin_amdgcn_s_setprio(0);

    asm volatile("s_waitcnt vmcnt(0)\n\ts_barrier" ::: "memory");
  }
#undef STAGE_AB

  if (n0 >= 2048) {
#pragma unroll
    for (int i = 0; i < 4; ++i)
#pragma unroll
      for (int j = 0; j < 4; ++j) {
        const int row0 = m0 + wm + i * 16 + quad * 4;
        const int col  = n0 - 2048 + wn + j * 16 + l15;
        const float bv = b_v[col];
        half4 pk;
        pk[0] = (_Float16)(acc[i][j][0] + bv);
        pk[1] = (_Float16)(acc[i][j][1] + bv);
        pk[2] = (_Float16)(acc[i][j][2] + bv);
        pk[3] = (_Float16)(acc[i][j][3] + bv);
        *(half4*)&vtb[(size_t)col * BL + row0] = pk;
      }
  } else {
    // 0.125 * log2(e): softmax computed as exp2 of these logits
    const float sc2 = (n0 + wn >= 1024) ? 0.18033688011112042f : 1.0f;
#pragma unroll
    for (int i = 0; i < 4; ++i)
#pragma unroll
      for (int j = 0; j < 4; ++j) {
        const int row0 = m0 + wm + i * 16 + quad * 4;
        const int col  = n0 + wn + j * 16 + l15;
        const float bv = b_kq[col];
#pragma unroll
        for (int r = 0; r < 4; ++r)
          kqb[(size_t)(row0 + r) * 2048 + col] = f2bf((acc[i][j][r] + bv) * sc2);
      }
  }
}

// ---------------- output GEMM (fp16, LDS double-buffer pipeline) ------------
// Per half-K-step: [vmcnt(0)+barrier][STAGE(next)->alt buf][frag-read cur]
// [MFMA]. Stage->wait distance = one full phase; 1 barrier per half-step.
// LDS 48KB; grid (512 blocks = 2/CU) binds occupancy, so dbuf is free.

__global__ __launch_bounds__(256, 2) void gemm_out(
    const _Float16* __restrict__ A, const _Float16* __restrict__ Bt,
    const float* __restrict__ bias, float* __restrict__ C)
{
  const int tid  = threadIdx.x;
  const int lane = tid & 63;
  const int w    = tid >> 6;
  const int wm   = (w >> 1) * 64;   // 0 / 64
  const int wn   = (w & 1) * 32;    // 0 / 32
  const int n0   = blockIdx.x * 64;
  const int m0   = blockIdx.y * 128;
  const int quad = lane >> 4;
  const int l15  = lane & 15;
  const int K    = 1024;

  __shared__ __align__(16) _Float16 As0[128 * 64];
  __shared__ __align__(16) _Float16 Bs0[64 * 64];
  __shared__ __align__(16) _Float16 As1[128 * 64];
  __shared__ __align__(16) _Float16 Bs1[64 * 64];

  const int srow = lane >> 3;
  const int sc   = (lane & 7) ^ srow;

  const _Float16* gA = A  + (size_t)(m0 + w * 32 + srow) * K + sc * 8;
  const _Float16* gB = Bt + (size_t)(n0 + w * 16 + srow) * K + sc * 8;

#define STAGE_AB(K0, AS, BS)                                                   \
  {                                                                            \
    _Pragma("unroll")                                                          \
    for (int i = 0; i < 4; ++i)                                                \
      load_lds16(gA + (size_t)i * 8 * K + (K0),                                \
                 &AS[(w * 32 + i * 8) * 64 + lane * 8]);                       \
    _Pragma("unroll")                                                          \
    for (int i = 0; i < 2; ++i)                                                \
      load_lds16(gB + (size_t)i * 8 * K + (K0),                                \
                 &BS[(w * 16 + i * 8) * 64 + lane * 8]);                       \
  }

// One half-K-step on buffer (AS,BS); prefetch KNEXT into (ASN,BSN).
// Safety: STAGE into (ASN,BSN) only overwrites data consumed 2 phases ago
// (barrier chain guarantees all waves' MFMAs consumed their frag reads
// before they arrive at the next barrier). vmcnt(0) at head waits for the
// loads issued one full phase earlier.
#define HALFSTEP(AS, BS, KNEXT, ASN, BSN)                                      \
  {                                                                            \
    asm volatile("s_waitcnt vmcnt(0)\n\ts_barrier" ::: "memory");              \
    if ((KNEXT) < K) STAGE_AB((KNEXT), ASN, BSN);                              \
    half8 af[2][4], bf[2][2];                                                  \
    _Pragma("unroll")                                                          \
    for (int kf = 0; kf < 2; ++kf) {                                           \
      _Pragma("unroll")                                                        \
      for (int t = 0; t < 4; ++t) {                                            \
        const int ra = wm + t * 16 + l15;                                      \
        const int pa = (kf * 4 + quad) ^ (ra & 7);                             \
        af[kf][t] = *(const half8*)&AS[ra * 64 + pa * 8];                      \
      }                                                                        \
      _Pragma("unroll")                                                        \
      for (int t = 0; t < 2; ++t) {                                            \
        const int rb = wn + t * 16 + l15;                                      \
        const int pb = (kf * 4 + quad) ^ (rb & 7);                             \
        bf[kf][t] = *(const half8*)&BS[rb * 64 + pb * 8];                      \
      }                                                                        \
    }                                                                          \
    __builtin_amdgcn_s_setprio(1);                                             \
    _Pragma("unroll")                                                          \
    for (int kf = 0; kf < 2; ++kf)                                             \
      _Pragma("unroll")                                                        \
      for (int i = 0; i < 4; ++i)                                              \
        _Pragma("unroll")                                                      \
        for (int j = 0; j < 2; ++j)                                            \
          acc[i][j] = __builtin_amdgcn_mfma_f32_16x16x32_f16(                  \
              af[kf][i], bf[kf][j], acc[i][j], 0, 0, 0);                       \
    __builtin_amdgcn_s_setprio(0);                                             \
  }

  f32x4 acc[4][2] = {};

  STAGE_AB(0, As0, Bs0);

#pragma unroll 1
  for (int k0 = 0; k0 < K; k0 += 128) {
    HALFSTEP(As0, Bs0, k0 + 64, As1, Bs1)
    HALFSTEP(As1, Bs1, k0 + 128, As0, Bs0)
  }
#undef STAGE_AB
#undef HALFSTEP

#pragma unroll
  for (int i = 0; i < 4; ++i)
#pragma unroll
    for (int j = 0; j < 2; ++j) {
      const int row0 = m0 + wm + i * 16 + quad * 4;
      const int col  = n0 + wn + j * 16 + l15;
      const float bv = bias[col];
#pragma unroll
      for (int r = 0; r < 4; ++r)
        C[(size_t)(row0 + r) * DM + col] = acc[i][j][r] + bv;
    }
}

// ---------------- flash attention (R14-exact: R11 structure + setprio) ------
// kq: bf16 [BL][2048] (k cols 0..1023, q cols 1024..2047 pre-scaled 0.125*log2e)
// vt: fp16 [1024][BL] (V^T); att: fp16 [BL][1024]
// 1024 blocks, heavy q-tiles first, 4 blocks/CU. Per tile: counted-vmcnt
// K/V pipeline (never drain to 0 in-loop), base-2 softmax, defer-max THR=8.

__global__ __launch_bounds__(256) void attn_mfma(
    const unsigned short* __restrict__ kq, const _Float16* __restrict__ vt,
    _Float16* __restrict__ att)
{
  const int tid  = threadIdx.x;
  const int lane = tid & 63;
  const int w    = tid >> 6;
  const int bx   = blockIdx.x;
  const int qt   = 31 - (bx >> 5);   // heavy q-tiles first
  const int bh   = bx & 31;
  const int b    = bh >> 4;
  const int h    = bh & 15;
  const int q0   = qt * 64;
  const int quad = lane >> 4;
  const int l15  = lane & 15;

  __shared__ __align__(16) unsigned short Ks[128 * 64];  // keys x d, bf16 (16KB)
  __shared__ __align__(16) _Float16      Vs[64 * 128];   // d x keys, fp16 (16KB)

  // ---- stage Q (64x64) into Ks region, read frags, then reuse Ks for K ----
#pragma unroll
  for (int i = 0; i < 2; ++i) {
    const int L = i * 256 + tid;        // 0..511
    const int row = L >> 3, c = L & 7;
    const unsigned short* g = kq + (size_t)(b * LSEQ + q0 + row) * 2048
                                 + DM + h * 64 + ((c ^ (row & 7)) * 8);
    load_lds16(g, &Ks[(size_t)L * 8]);
  }
  asm volatile("s_waitcnt vmcnt(0)\n\ts_barrier" ::: "memory");
  frag_ab qa[2];
#pragma unroll
  for (int kf = 0; kf < 2; ++kf) {
    const int row = w * 16 + l15;
    const int c = (kf * 4 + quad) ^ (row & 7);
    qa[kf] = *(const frag_ab*)&Ks[row * 64 + c * 8];
  }
  asm volatile("s_waitcnt lgkmcnt(0)\n\ts_barrier" ::: "memory");  // qa read; Ks free

  const int nk = (qt + 2) >> 1;

  // staging helpers: 4 DMA loads per thread each
#define STAGE_K(K0)                                                            \
  {                                                                            \
    _Pragma("unroll")                                                          \
    for (int i = 0; i < 4; ++i) {                                              \
      const int L = i * 256 + tid;                                             \
      const int row = L >> 3, c = L & 7;                                       \
      const unsigned short* g = kq + (size_t)(b * LSEQ + (K0) + row) * 2048    \
                                   + h * 64 + ((c ^ (row & 7)) * 8);           \
      load_lds16(g, &Ks[(size_t)L * 8]);                                       \
    }                                                                          \
  }
#define STAGE_V(K0)                                                            \
  {                                                                            \
    _Pragma("unroll")                                                          \
    for (int i = 0; i < 4; ++i) {                                              \
      const int L = i * 256 + tid;                                             \
      const int row = L >> 4, c16 = L & 15;                                    \
      const _Float16* g = vt + (size_t)(h * 64 + row) * BL                     \
                             + b * LSEQ + (K0) + ((c16 ^ (row & 15)) * 8);     \
      load_lds16(g, &Vs[(size_t)L * 8]);                                       \
    }                                                                          \
  }

  STAGE_K(0);
  STAGE_V(0);

  f32x4 oacc[4] = {};
  float mrow = -3e38f, lrow = 0.f;

  for (int kt = 0; kt < nk; ++kt) {
    const int k0 = kt * 128;
    const bool more = (kt + 1 < nk);

    // K(kt) landed (own 4 oldest); V(kt) may still be in flight
    asm volatile("s_waitcnt vmcnt(4)\n\ts_barrier" ::: "memory");

    // S^T = K @ Q^T : st[mt][r] = score(key = k0+mt*16+quad*4+r, qrow = l15)
    f32x4 st[8];
    __builtin_amdgcn_s_setprio(1);
#pragma unroll
    for (int mt = 0; mt < 8; ++mt) {
      f32x4 s = {};
#pragma unroll
      for (int kf = 0; kf < 2; ++kf) {
        const int row = mt * 16 + l15;
        const int c = (kf * 4 + quad) ^ (row & 7);
        const frag_ab kfrag = *(const frag_ab*)&Ks[row * 64 + c * 8];
        s = __builtin_amdgcn_mfma_f32_16x16x32_bf16(kfrag, qa[kf], s, 0, 0, 0);
      }
      st[mt] = s;
    }
    __builtin_amdgcn_s_setprio(0);

    // all waves done reading Ks -> safe to overwrite with K(kt+1)
    asm volatile("s_waitcnt lgkmcnt(0)\n\ts_barrier" ::: "memory");
    if (more) STAGE_K(k0 + 128);   // hides under softmax + PV

    if (kt == nk - 1) {   // causal mask (last tile only)
      const int qg = q0 + w * 16 + l15;
#pragma unroll
      for (int mt = 0; mt < 8; ++mt)
#pragma unroll
        for (int r = 0; r < 4; ++r)
          if (k0 + mt * 16 + quad * 4 + r > qg) st[mt][r] = -3e38f;
    }

    // ---- online softmax (base-2), defer-max THR=8 ----
    float mx = fmaxf(st[0][0], st[0][1]);
    mx = fmaxf(fmaxf(mx, st[0][2]), st[0][3]);
#pragma unroll
    for (int mt = 1; mt < 8; ++mt) {
      mx = fmaxf(fmaxf(mx, st[mt][0]), st[mt][1]);
      mx = fmaxf(fmaxf(mx, st[mt][2]), st[mt][3]);
    }
    mx = fmaxf(mx, __shfl_xor(mx, 16));
    mx = fmaxf(mx, __shfl_xor(mx, 32));

    if (!__all(mx - mrow <= 8.0f)) {     // rare: real max growth -> rescale
      const float mnew  = fmaxf(mrow, mx);
      const float alpha = __builtin_amdgcn_exp2f(mrow - mnew);
      float aq[4];
#pragma unroll
      for (int r = 0; r < 4; ++r) aq[r] = __shfl(alpha, quad * 4 + r);
#pragma unroll
      for (int dt = 0; dt < 4; ++dt)
#pragma unroll
        for (int r = 0; r < 4; ++r) oacc[dt][r] *= aq[r];
      lrow *= alpha;
      mrow = mnew;
    }

    // P = exp2(st - mrow), packed fp16; rsum with 4-way ILP
    half4 pf[8];
    float rs0 = 0.f, rs1 = 0.f, rs2 = 0.f, rs3 = 0.f;
#pragma unroll
    for (int mt = 0; mt < 8; ++mt) {
      const float e0 = __builtin_amdgcn_exp2f(st[mt][0] - mrow);
      const float e1 = __builtin_amdgcn_exp2f(st[mt][1] - mrow);
      const float e2 = __builtin_amdgcn_exp2f(st[mt][2] - mrow);
      const float e3 = __builtin_amdgcn_exp2f(st[mt][3] - mrow);
      rs0 += e0; rs1 += e1; rs2 += e2; rs3 += e3;
      const half2_t p01 = pkrtz(e0, e1);
      const half2_t p23 = pkrtz(e2, e3);
      half4 p;
      p[0] = p01[0]; p[1] = p01[1]; p[2] = p23[0]; p[3] = p23[1];
      pf[mt] = p;
    }
    float rsum = (rs0 + rs1) + (rs2 + rs3);
    rsum += __shfl_xor(rsum, 16);
    rsum += __shfl_xor(rsum, 32);
    lrow += rsum;

    // V(kt) landed (own 4 oldest remaining); K(kt+1) may still be in flight
    if (more) {
      asm volatile("s_waitcnt vmcnt(4)\n\ts_barrier" ::: "memory");
    } else {
      asm volatile("s_waitcnt vmcnt(0)\n\ts_barrier" ::: "memory");
    }

    // O += P @ V : P is register-local (st C-layout == A-layout of K=16 mfma)
    __builtin_amdgcn_s_setprio(1);
#pragma unroll
    for (int c8 = 0; c8 < 8; ++c8) {
#pragma unroll
      for (int dt = 0; dt < 4; ++dt) {
        const int g16 = 2 * c8 + (quad >> 1);
        const half4 vf = *(const half4*)&Vs[(dt * 16 + l15) * 128
                                            + ((g16 ^ l15) << 3) + ((quad & 1) << 2)];
        oacc[dt] = __builtin_amdgcn_mfma_f32_16x16x16f16(pf[c8], vf, oacc[dt], 0, 0, 0);
      }
    }
    __builtin_amdgcn_s_setprio(0);

    if (more) {
      // all waves done reading Vs -> safe to overwrite with V(kt+1)
      asm volatile("s_waitcnt lgkmcnt(0)\n\ts_barrier" ::: "memory");
      STAGE_V(k0 + 128);   // hides under next S^T
    }
  }

  // epilogue: lane holds O[qrow=quad*4+r][d=dt*16+l15]; divide by l, store fp16
  float lq[4];
#pragma unroll
  for (int r = 0; r < 4; ++r) lq[r] = 1.0f / __shfl(lrow, quad * 4 + r);
#pragma unroll
  for (int dt = 0; dt < 4; ++dt)
#pragma unroll
    for (int r = 0; r < 4; ++r) {
      const int row = b * LSEQ + q0 + w * 16 + quad * 4 + r;
      const int col = h * 64 + dt * 16 + l15;
      att[(size_t)row * DM + col] = (_Float16)(oacc[dt][r] * lq[r]);
    }
#undef STAGE_K
#undef STAGE_V
}

// ---------------- launcher ----------------

extern "C" void kernel_launch(void* const* d_in, const int* in_sizes, int n_in,
                              void* d_out, int out_size, void* d_ws, size_t ws_size,
                              hipStream_t stream)
{
  const float* x    = (const float*)d_in[0];
  const float* W_kq = (const float*)d_in[1];
  const float* b_kq = (const float*)d_in[2];
  const float* W_v  = (const float*)d_in[3];
  const float* b_v  = (const float*)d_in[4];
  const float* W_o  = (const float*)d_in[5];
  const float* b_o  = (const float*)d_in[6];

  unsigned short* ws   = (unsigned short*)d_ws;
  unsigned short* xb   = ws;                    // 4096*1024 bf16
  unsigned short* wcat = xb   + 4194304;        // 3072*1024 bf16
  _Float16*       wot  = (_Float16*)(wcat + 3145728);      // 1024*1024 fp16
  unsigned short* kqb  = (unsigned short*)(wot + 1048576); // 4096*2048 bf16
  _Float16*       vtb  = (_Float16*)(kqb + 8388608);       // 1024*4096 fp16
  _Float16*       attb = vtb + 4194304;         // 4096*1024 fp16

  // merged prep (cast + 3 transposes)
  prep_kernel<<<8192, 256, 0, stream>>>(x, xb, W_kq, W_v, W_o, wcat, wot);
  // fused kq + v GEMM (24 x 32 = 768 blocks)
  gemm_kqv<<<dim3(24, 32), 256, 0, stream>>>(xb, wcat, b_kq, b_v, kqb, vtb);
  // attention (1024 blocks)
  attn_mfma<<<1024, 256, 0, stream>>>(kqb, vtb, attb);
  // out = att @ Wo^T + b_o (16 x 32 = 512 blocks, 128x64 tiles)
  gemm_out<<<dim3(16, 32), 256, 0, stream>>>(attb, wot, b_o, (float*)d_out);
}

// Round 11
// 168.970 us; speedup vs baseline: 1.0565x; 1.0386x over previous
//
#include <hip/hip_runtime.h>
#include <cstdint>

// CausalSelfAttention B=2 L=2048 D=1024 H=16 dh=64, fp32 in/out.
// R19 = R14-exact (best measured 169.4us) + T1 XCD-chunked swizzle on
// gemm_kqv ONLY. R17's gemm_out dbuf regressed (+6us: STAGE-before-ds_read
// adds LDS port contention; R14's stage-under-MFMA is the right overlap) —
// reverted. Swizzle theory: gridDim.x=24 = 0 mod 8 means B-panel sharers
// already co-locate per XCD, but the 24 sharers of each A-panel spread over
// all 8 XCDs (bid%8 dispatch) -> ~8x redundant A fetches from L3 feeding
// the per-iter vmcnt(0) drain. Chunked remap (XCD k <- bids [96k,96k+96) =
// 4 complete by-rows) co-locates A-sharers; 768=8x96 -> bijective.

#define LSEQ 2048
#define DM   1024
#define BL   4096   // B * LSEQ

using frag_ab = __attribute__((ext_vector_type(8))) short;     // 8 bf16
using half8   = __attribute__((ext_vector_type(8))) _Float16;  // 8 fp16
using half4   = __attribute__((ext_vector_type(4))) _Float16;
using half2_t = __attribute__((ext_vector_type(2))) _Float16;
using fp16x2  = __attribute__((ext_vector_type(2))) __fp16;
using f32x4   = __attribute__((ext_vector_type(4))) float;

__device__ __forceinline__ unsigned short f2bf(float f) {
  unsigned int u = __float_as_uint(f);
  u += 0x7fffu + ((u >> 16) & 1u);   // RNE (finite inputs only)
  return (unsigned short)(u >> 16);
}

__device__ __forceinline__ half2_t pkrtz(float a, float b) {
  const fp16x2 r = __builtin_amdgcn_cvt_pkrtz(a, b);
  return __builtin_bit_cast(half2_t, r);
}

__device__ __forceinline__ void load_lds16(const void* g, void* l) {
  __builtin_amdgcn_global_load_lds(
      (const __attribute__((address_space(1))) unsigned int*)g,
      (__attribute__((address_space(3))) unsigned int*)l, 16, 0, 0);
}

// ---------------- merged prep kernel ----------------
// bid <  4096          : cast x -> bf16 (1 float4 per thread)
// 4096 <= bid < 6144   : W_kq (1024x2048) -> wcat bf16 [2048x1024]
// 6144 <= bid < 7168   : W_v  (1024x1024) -> wcat+2M bf16
// 7168 <= bid < 8192   : W_o  (1024x1024) -> wot fp16

__global__ __launch_bounds__(256) void prep_kernel(
    const float* __restrict__ x, unsigned short* __restrict__ xb,
    const float* __restrict__ W_kq, const float* __restrict__ W_v,
    const float* __restrict__ W_o,
    unsigned short* __restrict__ wcat, _Float16* __restrict__ wot)
{
  const int bid = blockIdx.x;
  const int tid = threadIdx.x;

  if (bid < 4096) {
    const int i = bid * 256 + tid;
    const float4 v = *(const float4*)&x[(size_t)i * 4];
    ushort4 o;
    o.x = f2bf(v.x); o.y = f2bf(v.y); o.z = f2bf(v.z); o.w = f2bf(v.w);
    *(ushort4*)&xb[(size_t)i * 4] = o;
    return;
  }

  __shared__ float tile[32][33];
  const int r  = tid >> 3;
  const int c4 = (tid & 7) * 4;

  const float* W;
  int N, nb, kb, which;
  if (bid < 6144) {
    const int b2 = bid - 4096;
    W = W_kq; N = 2048; nb = (b2 & 63) * 32; kb = (b2 >> 6) * 32; which = 0;
  } else if (bid < 7168) {
    const int b2 = bid - 6144;
    W = W_v;  N = 1024; nb = (b2 & 31) * 32; kb = (b2 >> 5) * 32; which = 1;
  } else {
    const int b2 = bid - 7168;
    W = W_o;  N = 1024; nb = (b2 & 31) * 32; kb = (b2 >> 5) * 32; which = 2;
  }

  const float4 v = *(const float4*)&W[(size_t)(kb + r) * N + nb + c4];
  tile[r][c4 + 0] = v.x; tile[r][c4 + 1] = v.y;
  tile[r][c4 + 2] = v.z; tile[r][c4 + 3] = v.w;
  __syncthreads();

  if (which == 2) {
    half4 o;
    o[0] = (_Float16)tile[c4 + 0][r];
    o[1] = (_Float16)tile[c4 + 1][r];
    o[2] = (_Float16)tile[c4 + 2][r];
    o[3] = (_Float16)tile[c4 + 3][r];
    *(half4*)&wot[(size_t)(nb + r) * 1024 + kb + c4] = o;
  } else {
    ushort4 o;
    o.x = f2bf(tile[c4 + 0][r]);
    o.y = f2bf(tile[c4 + 1][r]);
    o.z = f2bf(tile[c4 + 2][r]);
    o.w = f2bf(tile[c4 + 3][r]);
    unsigned short* dst = (which == 0) ? wcat : wcat + 2097152;
    *(ushort4*)&dst[(size_t)(nb + r) * 1024 + kb + c4] = o;
  }
}

// ---------------- fused kqv GEMM (frag-preload + XCD-chunked swizzle) -------
// A = xb [4096x1024] bf16, Bt = wcat [3072x1024] bf16
// cols <  2048 : kqb[row][col] = bf16((acc+b_kq[col]) * (col>=1024 ? s : 1))
//                s = 0.125 * log2(e)  (softmax runs in base-2)
// cols >= 2048 : vtb[col-2048][row] = fp16(acc + b_v[col-2048])   (V^T)
// Launched as 768 1-D blocks; bid swizzled so XCD k owns bids [96k,96k+96)
// = 4 complete A-panel rows (A-sharers co-locate in one L2).

__global__ __launch_bounds__(256, 3) void gemm_kqv(
    const unsigned short* __restrict__ A, const unsigned short* __restrict__ Bt,
    const float* __restrict__ b_kq, const float* __restrict__ b_v,
    unsigned short* __restrict__ kqb, _Float16* __restrict__ vtb)
{
  const int tid  = threadIdx.x;
  const int lane = tid & 63;
  const int w    = tid >> 6;
  const int wm   = (w >> 1) * 64;
  const int wn   = (w & 1) * 64;

  // XCD-chunked bijective swizzle: 768 = 8 XCDs x 96
  const int bid  = blockIdx.x;
  const int nb2  = (bid & 7) * 96 + (bid >> 3);   // new linear block id
  const int n0   = (nb2 % 24) * 128;
  const int m0   = (nb2 / 24) * 128;

  const int quad = lane >> 4;
  const int l15  = lane & 15;
  const int K    = 1024;

  __shared__ __align__(16) unsigned short As[128 * 64];
  __shared__ __align__(16) unsigned short Bs[128 * 64];

  const int srow = lane >> 3;
  const int sc   = (lane & 7) ^ srow;

  const unsigned short* gA = A  + (size_t)(m0 + w * 32 + srow) * K + sc * 8;
  const unsigned short* gB = Bt + (size_t)(n0 + w * 32 + srow) * K + sc * 8;

#define STAGE_AB(K0)                                                           \
  {                                                                            \
    _Pragma("unroll")                                                          \
    for (int i = 0; i < 4; ++i) {                                              \
      load_lds16(gA + (size_t)i * 8 * K + (K0),                                \
                 &As[(w * 32 + i * 8) * 64 + lane * 8]);                       \
      load_lds16(gB + (size_t)i * 8 * K + (K0),                                \
                 &Bs[(w * 32 + i * 8) * 64 + lane * 8]);                       \
    }                                                                          \
  }

  f32x4 acc[4][4] = {};

  STAGE_AB(0);
  asm volatile("s_waitcnt vmcnt(0)\n\ts_barrier" ::: "memory");

  for (int k0 = 0; k0 < K; k0 += 64) {
    // LDS -> registers: all fragments of this K-tile
    frag_ab af[2][4], bf[2][4];
#pragma unroll
    for (int kf = 0; kf < 2; ++kf)
#pragma unroll
      for (int t = 0; t < 4; ++t) {
        const int ra = wm + t * 16 + l15;
        const int pa = (kf * 4 + quad) ^ (ra & 7);
        af[kf][t] = *(const frag_ab*)&As[ra * 64 + pa * 8];
        const int rb = wn + t * 16 + l15;
        const int pb = (kf * 4 + quad) ^ (rb & 7);
        bf[kf][t] = *(const frag_ab*)&Bs[rb * 64 + pb * 8];
      }
    // all ds_reads done -> LDS free for next stage
    asm volatile("s_waitcnt lgkmcnt(0)\n\ts_barrier" ::: "memory");
    if (k0 + 64 < K) STAGE_AB(k0 + 64);   // flies under the MFMAs below

    __builtin_amdgcn_s_setprio(1);
#pragma unroll
    for (int kf = 0; kf < 2; ++kf)
#pragma unroll
      for (int i = 0; i < 4; ++i)
#pragma unroll
        for (int j = 0; j < 4; ++j)
          acc[i][j] = __builtin_amdgcn_mfma_f32_16x16x32_bf16(
              af[kf][i], bf[kf][j], acc[i][j], 0, 0, 0);
    __builtin_amdgcn_s_setprio(0);

    asm volatile("s_waitcnt vmcnt(0)\n\ts_barrier" ::: "memory");
  }
#undef STAGE_AB

  if (n0 >= 2048) {
#pragma unroll
    for (int i = 0; i < 4; ++i)
#pragma unroll
      for (int j = 0; j < 4; ++j) {
        const int row0 = m0 + wm + i * 16 + quad * 4;
        const int col  = n0 - 2048 + wn + j * 16 + l15;
        const float bv = b_v[col];
        half4 pk;
        pk[0] = (_Float16)(acc[i][j][0] + bv);
        pk[1] = (_Float16)(acc[i][j][1] + bv);
        pk[2] = (_Float16)(acc[i][j][2] + bv);
        pk[3] = (_Float16)(acc[i][j][3] + bv);
        *(half4*)&vtb[(size_t)col * BL + row0] = pk;
      }
  } else {
    // 0.125 * log2(e): softmax computed as exp2 of these logits
    const float sc2 = (n0 + wn >= 1024) ? 0.18033688011112042f : 1.0f;
#pragma unroll
    for (int i = 0; i < 4; ++i)
#pragma unroll
      for (int j = 0; j < 4; ++j) {
        const int row0 = m0 + wm + i * 16 + quad * 4;
        const int col  = n0 + wn + j * 16 + l15;
        const float bv = b_kq[col];
#pragma unroll
        for (int r = 0; r < 4; ++r)
          kqb[(size_t)(row0 + r) * 2048 + col] = f2bf((acc[i][j][r] + bv) * sc2);
      }
  }
}

// ---------------- output GEMM (fp16, frag-preload pipeline, R14) ------------

__global__ __launch_bounds__(256, 2) void gemm_out(
    const _Float16* __restrict__ A, const _Float16* __restrict__ Bt,
    const float* __restrict__ bias, float* __restrict__ C)
{
  const int tid  = threadIdx.x;
  const int lane = tid & 63;
  const int w    = tid >> 6;
  const int wm   = (w >> 1) * 64;   // 0 / 64
  const int wn   = (w & 1) * 32;    // 0 / 32
  const int n0   = blockIdx.x * 64;
  const int m0   = blockIdx.y * 128;
  const int quad = lane >> 4;
  const int l15  = lane & 15;
  const int K    = 1024;

  __shared__ __align__(16) _Float16 As[128 * 64];
  __shared__ __align__(16) _Float16 Bs[64 * 64];

  const int srow = lane >> 3;
  const int sc   = (lane & 7) ^ srow;

  const _Float16* gA = A  + (size_t)(m0 + w * 32 + srow) * K + sc * 8;
  const _Float16* gB = Bt + (size_t)(n0 + w * 16 + srow) * K + sc * 8;

#define STAGE_AB(K0)                                                           \
  {                                                                            \
    _Pragma("unroll")                                                          \
    for (int i = 0; i < 4; ++i)                                                \
      load_lds16(gA + (size_t)i * 8 * K + (K0),                                \
                 &As[(w * 32 + i * 8) * 64 + lane * 8]);                       \
    _Pragma("unroll")                                                          \
    for (int i = 0; i < 2; ++i)                                                \
      load_lds16(gB + (size_t)i * 8 * K + (K0),                                \
                 &Bs[(w * 16 + i * 8) * 64 + lane * 8]);                       \
  }

  f32x4 acc[4][2] = {};

  STAGE_AB(0);
  asm volatile("s_waitcnt vmcnt(0)\n\ts_barrier" ::: "memory");

  for (int k0 = 0; k0 < K; k0 += 64) {
    half8 af[2][4], bf[2][2];
#pragma unroll
    for (int kf = 0; kf < 2; ++kf) {
#pragma unroll
      for (int t = 0; t < 4; ++t) {
        const int ra = wm + t * 16 + l15;
        const int pa = (kf * 4 + quad) ^ (ra & 7);
        af[kf][t] = *(const half8*)&As[ra * 64 + pa * 8];
      }
#pragma unroll
      for (int t = 0; t < 2; ++t) {
        const int rb = wn + t * 16 + l15;
        const int pb = (kf * 4 + quad) ^ (rb & 7);
        bf[kf][t] = *(const half8*)&Bs[rb * 64 + pb * 8];
      }
    }
    asm volatile("s_waitcnt lgkmcnt(0)\n\ts_barrier" ::: "memory");
    if (k0 + 64 < K) STAGE_AB(k0 + 64);

    __builtin_amdgcn_s_setprio(1);
#pragma unroll
    for (int kf = 0; kf < 2; ++kf)
#pragma unroll
      for (int i = 0; i < 4; ++i)
#pragma unroll
        for (int j = 0; j < 2; ++j)
          acc[i][j] = __builtin_amdgcn_mfma_f32_16x16x32_f16(
              af[kf][i], bf[kf][j], acc[i][j], 0, 0, 0);
    __builtin_amdgcn_s_setprio(0);

    asm volatile("s_waitcnt vmcnt(0)\n\ts_barrier" ::: "memory");
  }
#undef STAGE_AB

#pragma unroll
  for (int i = 0; i < 4; ++i)
#pragma unroll
    for (int j = 0; j < 2; ++j) {
      const int row0 = m0 + wm + i * 16 + quad * 4;
      const int col  = n0 + wn + j * 16 + l15;
      const float bv = bias[col];
#pragma unroll
      for (int r = 0; r < 4; ++r)
        C[(size_t)(row0 + r) * DM + col] = acc[i][j][r] + bv;
    }
}

// ---------------- flash attention (R14-exact: R11 structure + setprio) ------
// kq: bf16 [BL][2048] (k cols 0..1023, q cols 1024..2047 pre-scaled 0.125*log2e)
// vt: fp16 [1024][BL] (V^T); att: fp16 [BL][1024]
// 1024 blocks, heavy q-tiles first, 4 blocks/CU. Per tile: counted-vmcnt
// K/V pipeline (never drain to 0 in-loop), base-2 softmax, defer-max THR=8.

__global__ __launch_bounds__(256) void attn_mfma(
    const unsigned short* __restrict__ kq, const _Float16* __restrict__ vt,
    _Float16* __restrict__ att)
{
  const int tid  = threadIdx.x;
  const int lane = tid & 63;
  const int w    = tid >> 6;
  const int bx   = blockIdx.x;
  const int qt   = 31 - (bx >> 5);   // heavy q-tiles first
  const int bh   = bx & 31;
  const int b    = bh >> 4;
  const int h    = bh & 15;
  const int q0   = qt * 64;
  const int quad = lane >> 4;
  const int l15  = lane & 15;

  __shared__ __align__(16) unsigned short Ks[128 * 64];  // keys x d, bf16 (16KB)
  __shared__ __align__(16) _Float16      Vs[64 * 128];   // d x keys, fp16 (16KB)

  // ---- stage Q (64x64) into Ks region, read frags, then reuse Ks for K ----
#pragma unroll
  for (int i = 0; i < 2; ++i) {
    const int L = i * 256 + tid;        // 0..511
    const int row = L >> 3, c = L & 7;
    const unsigned short* g = kq + (size_t)(b * LSEQ + q0 + row) * 2048
                                 + DM + h * 64 + ((c ^ (row & 7)) * 8);
    load_lds16(g, &Ks[(size_t)L * 8]);
  }
  asm volatile("s_waitcnt vmcnt(0)\n\ts_barrier" ::: "memory");
  frag_ab qa[2];
#pragma unroll
  for (int kf = 0; kf < 2; ++kf) {
    const int row = w * 16 + l15;
    const int c = (kf * 4 + quad) ^ (row & 7);
    qa[kf] = *(const frag_ab*)&Ks[row * 64 + c * 8];
  }
  asm volatile("s_waitcnt lgkmcnt(0)\n\ts_barrier" ::: "memory");  // qa read; Ks free

  const int nk = (qt + 2) >> 1;

  // staging helpers: 4 DMA loads per thread each
#define STAGE_K(K0)                                                            \
  {                                                                            \
    _Pragma("unroll")                                                          \
    for (int i = 0; i < 4; ++i) {                                              \
      const int L = i * 256 + tid;                                             \
      const int row = L >> 3, c = L & 7;                                       \
      const unsigned short* g = kq + (size_t)(b * LSEQ + (K0) + row) * 2048    \
                                   + h * 64 + ((c ^ (row & 7)) * 8);           \
      load_lds16(g, &Ks[(size_t)L * 8]);                                       \
    }                                                                          \
  }
#define STAGE_V(K0)                                                            \
  {                                                                            \
    _Pragma("unroll")                                                          \
    for (int i = 0; i < 4; ++i) {                                              \
      const int L = i * 256 + tid;                                             \
      const int row = L >> 4, c16 = L & 15;                                    \
      const _Float16* g = vt + (size_t)(h * 64 + row) * BL                     \
                             + b * LSEQ + (K0) + ((c16 ^ (row & 15)) * 8);     \
      load_lds16(g, &Vs[(size_t)L * 8]);                                       \
    }                                                                          \
  }

  STAGE_K(0);
  STAGE_V(0);

  f32x4 oacc[4] = {};
  float mrow = -3e38f, lrow = 0.f;

  for (int kt = 0; kt < nk; ++kt) {
    const int k0 = kt * 128;
    const bool more = (kt + 1 < nk);

    // K(kt) landed (own 4 oldest); V(kt) may still be in flight
    asm volatile("s_waitcnt vmcnt(4)\n\ts_barrier" ::: "memory");

    // S^T = K @ Q^T : st[mt][r] = score(key = k0+mt*16+quad*4+r, qrow = l15)
    f32x4 st[8];
    __builtin_amdgcn_s_setprio(1);
#pragma unroll
    for (int mt = 0; mt < 8; ++mt) {
      f32x4 s = {};
#pragma unroll
      for (int kf = 0; kf < 2; ++kf) {
        const int row = mt * 16 + l15;
        const int c = (kf * 4 + quad) ^ (row & 7);
        const frag_ab kfrag = *(const frag_ab*)&Ks[row * 64 + c * 8];
        s = __builtin_amdgcn_mfma_f32_16x16x32_bf16(kfrag, qa[kf], s, 0, 0, 0);
      }
      st[mt] = s;
    }
    __builtin_amdgcn_s_setprio(0);

    // all waves done reading Ks -> safe to overwrite with K(kt+1)
    asm volatile("s_waitcnt lgkmcnt(0)\n\ts_barrier" ::: "memory");
    if (more) STAGE_K(k0 + 128);   // hides under softmax + PV

    if (kt == nk - 1) {   // causal mask (last tile only)
      const int qg = q0 + w * 16 + l15;
#pragma unroll
      for (int mt = 0; mt < 8; ++mt)
#pragma unroll
        for (int r = 0; r < 4; ++r)
          if (k0 + mt * 16 + quad * 4 + r > qg) st[mt][r] = -3e38f;
    }

    // ---- online softmax (base-2), defer-max THR=8 ----
    float mx = fmaxf(st[0][0], st[0][1]);
    mx = fmaxf(fmaxf(mx, st[0][2]), st[0][3]);
#pragma unroll
    for (int mt = 1; mt < 8; ++mt) {
      mx = fmaxf(fmaxf(mx, st[mt][0]), st[mt][1]);
      mx = fmaxf(fmaxf(mx, st[mt][2]), st[mt][3]);
    }
    mx = fmaxf(mx, __shfl_xor(mx, 16));
    mx = fmaxf(mx, __shfl_xor(mx, 32));

    if (!__all(mx - mrow <= 8.0f)) {     // rare: real max growth -> rescale
      const float mnew  = fmaxf(mrow, mx);
      const float alpha = __builtin_amdgcn_exp2f(mrow - mnew);
      float aq[4];
#pragma unroll
      for (int r = 0; r < 4; ++r) aq[r] = __shfl(alpha, quad * 4 + r);
#pragma unroll
      for (int dt = 0; dt < 4; ++dt)
#pragma unroll
        for (int r = 0; r < 4; ++r) oacc[dt][r] *= aq[r];
      lrow *= alpha;
      mrow = mnew;
    }

    // P = exp2(st - mrow), packed fp16; rsum with 4-way ILP
    half4 pf[8];
    float rs0 = 0.f, rs1 = 0.f, rs2 = 0.f, rs3 = 0.f;
#pragma unroll
    for (int mt = 0; mt < 8; ++mt) {
      const float e0 = __builtin_amdgcn_exp2f(st[mt][0] - mrow);
      const float e1 = __builtin_amdgcn_exp2f(st[mt][1] - mrow);
      const float e2 = __builtin_amdgcn_exp2f(st[mt][2] - mrow);
      const float e3 = __builtin_amdgcn_exp2f(st[mt][3] - mrow);
      rs0 += e0; rs1 += e1; rs2 += e2; rs3 += e3;
      const half2_t p01 = pkrtz(e0, e1);
      const half2_t p23 = pkrtz(e2, e3);
      half4 p;
      p[0] = p01[0]; p[1] = p01[1]; p[2] = p23[0]; p[3] = p23[1];
      pf[mt] = p;
    }
    float rsum = (rs0 + rs1) + (rs2 + rs3);
    rsum += __shfl_xor(rsum, 16);
    rsum += __shfl_xor(rsum, 32);
    lrow += rsum;

    // V(kt) landed (own 4 oldest remaining); K(kt+1) may still be in flight
    if (more) {
      asm volatile("s_waitcnt vmcnt(4)\n\ts_barrier" ::: "memory");
    } else {
      asm volatile("s_waitcnt vmcnt(0)\n\ts_barrier" ::: "memory");
    }

    // O += P @ V : P is register-local (st C-layout == A-layout of K=16 mfma)
    __builtin_amdgcn_s_setprio(1);
#pragma unroll
    for (int c8 = 0; c8 < 8; ++c8) {
#pragma unroll
      for (int dt = 0; dt < 4; ++dt) {
        const int g16 = 2 * c8 + (quad >> 1);
        const half4 vf = *(const half4*)&Vs[(dt * 16 + l15) * 128
                                            + ((g16 ^ l15) << 3) + ((quad & 1) << 2)];
        oacc[dt] = __builtin_amdgcn_mfma_f32_16x16x16f16(pf[c8], vf, oacc[dt], 0, 0, 0);
      }
    }
    __builtin_amdgcn_s_setprio(0);

    if (more) {
      // all waves done reading Vs -> safe to overwrite with V(kt+1)
      asm volatile("s_waitcnt lgkmcnt(0)\n\ts_barrier" ::: "memory");
      STAGE_V(k0 + 128);   // hides under next S^T
    }
  }

  // epilogue: lane holds O[qrow=quad*4+r][d=dt*16+l15]; divide by l, store fp16
  float lq[4];
#pragma unroll
  for (int r = 0; r < 4; ++r) lq[r] = 1.0f / __shfl(lrow, quad * 4 + r);
#pragma unroll
  for (int dt = 0; dt < 4; ++dt)
#pragma unroll
    for (int r = 0; r < 4; ++r) {
      const int row = b * LSEQ + q0 + w * 16 + quad * 4 + r;
      const int col = h * 64 + dt * 16 + l15;
      att[(size_t)row * DM + col] = (_Float16)(oacc[dt][r] * lq[r]);
    }
#undef STAGE_K
#undef STAGE_V
}

// ---------------- launcher ----------------

extern "C" void kernel_launch(void* const* d_in, const int* in_sizes, int n_in,
                              void* d_out, int out_size, void* d_ws, size_t ws_size,
                              hipStream_t stream)
{
  const float* x    = (const float*)d_in[0];
  const float* W_kq = (const float*)d_in[1];
  const float* b_kq = (const float*)d_in[2];
  const float* W_v  = (const float*)d_in[3];
  const float* b_v  = (const float*)d_in[4];
  const float* W_o  = (const float*)d_in[5];
  const float* b_o  = (const float*)d_in[6];

  unsigned short* ws   = (unsigned short*)d_ws;
  unsigned short* xb   = ws;                    // 4096*1024 bf16
  unsigned short* wcat = xb   + 4194304;        // 3072*1024 bf16
  _Float16*       wot  = (_Float16*)(wcat + 3145728);      // 1024*1024 fp16
  unsigned short* kqb  = (unsigned short*)(wot + 1048576); // 4096*2048 bf16
  _Float16*       vtb  = (_Float16*)(kqb + 8388608);       // 1024*4096 fp16
  _Float16*       attb = vtb + 4194304;         // 4096*1024 fp16

  // merged prep (cast + 3 transposes)
  prep_kernel<<<8192, 256, 0, stream>>>(x, xb, W_kq, W_v, W_o, wcat, wot);
  // fused kq + v GEMM (768 1-D blocks, XCD-chunked swizzle inside)
  gemm_kqv<<<768, 256, 0, stream>>>(xb, wcat, b_kq, b_v, kqb, vtb);
  // attention (1024 blocks)
  attn_mfma<<<1024, 256, 0, stream>>>(kqb, vtb, attb);
  // out = att @ Wo^T + b_o (16 x 32 = 512 blocks, 128x64 tiles)
  gemm_out<<<dim3(16, 32), 256, 0, stream>>>(attb, wot, b_o, (float*)d_out);
}